// Round 4
// baseline (1326.854 us; speedup 1.0000x reference)
//
#include <hip/hip_runtime.h>
#include <math.h>

// ---------------------------------------------------------------------------
// SelfAttention (B=4, C=256, H=W=48, A=8, hid=512) on MI355X, bf16 MFMA.
// Pipeline (chunked over pairs to fit ws_size):
//   transpose/convert -> QKV proj GEMM -> flash attention -> out GEMM (+=).
// ---------------------------------------------------------------------------

typedef __bf16 bf16x8 __attribute__((ext_vector_type(8)));
typedef float f32x4 __attribute__((ext_vector_type(4)));

#define MFMA16(a, b, c) __builtin_amdgcn_mfma_f32_16x16x32_bf16(a, b, c, 0, 0, 0)

#define NTOK 2304
#define CIN 256
#define DTOT 4096
#define HID 512

__device__ __forceinline__ unsigned short f2bf(float f) {
  union { float f; unsigned int u; } v;
  v.f = f;
  unsigned int r = v.u + 0x7fffu + ((v.u >> 16) & 1u);  // RNE
  return (unsigned short)(r >> 16);
}

__device__ __forceinline__ void gload16(const void* g, void* l) {
  __builtin_amdgcn_global_load_lds(
      (const __attribute__((address_space(1))) unsigned int*)g,
      (__attribute__((address_space(3))) unsigned int*)l, 16, 0, 0);
}

__device__ __forceinline__ float rmax16(float v) {
  v = fmaxf(v, __shfl_xor(v, 1));
  v = fmaxf(v, __shfl_xor(v, 2));
  v = fmaxf(v, __shfl_xor(v, 4));
  v = fmaxf(v, __shfl_xor(v, 8));
  return v;
}
__device__ __forceinline__ float rsum16(float v) {
  v += __shfl_xor(v, 1);
  v += __shfl_xor(v, 2);
  v += __shfl_xor(v, 4);
  v += __shfl_xor(v, 8);
  return v;
}

// ---------------------------------------------------------------------------
// Transpose fp32 (R x C) -> bf16 (C x R).  block (32,8), grid (C/32, R/32).
// ---------------------------------------------------------------------------
__global__ void transpose_to_bf16(const float* __restrict__ src,
                                  unsigned short* __restrict__ dst,
                                  int R, int C) {
  __shared__ float tile[32][33];
  int c0 = blockIdx.x * 32, r0 = blockIdx.y * 32;
  int tx = threadIdx.x, ty0 = threadIdx.y;
#pragma unroll
  for (int i = 0; i < 4; i++) {
    int ty = ty0 + i * 8;
    tile[ty][tx] = src[(size_t)(r0 + ty) * C + c0 + tx];
  }
  __syncthreads();
#pragma unroll
  for (int i = 0; i < 4; i++) {
    int ty = ty0 + i * 8;
    dst[(size_t)(c0 + ty) * R + r0 + tx] = f2bf(tile[tx][ty]);
  }
}

// ---------------------------------------------------------------------------
// QKV projection: Out = T(tokens x 256) @ Wt^T + bias.  T:(token,c) bf16,
// Wt:(d,c) bf16 (caller pre-offsets to the chunk's d0 row).  Local pair
// p = b_idx*PAW + a_idx.  vlayout 0: Out[(p*2304+n)*512+e] (Q/K);
// vlayout 1: Out[(p*512+e)*2304+n] (V transposed).
// grid (tokens/128, PAW*4), block 256 (4 waves, each 64x64).
// ---------------------------------------------------------------------------
__global__ __launch_bounds__(256, 2) void proj_gemm(
    const unsigned short* __restrict__ T, const unsigned short* __restrict__ Wt,
    const float* __restrict__ bias, unsigned short* __restrict__ Out,
    int vlayout, int PAW) {
  __shared__ __align__(16) char smem[36864];
  unsigned short* As = (unsigned short*)smem;       // [128][64] bf16, swizzled
  unsigned short* Bs = As + 128 * 64;               // [128][64]
  const int tid = threadIdx.x;
  const int w = tid >> 6, lane = tid & 63;
  const int wr = w >> 1, wc = w & 1;
  const int l15 = lane & 15, h = lane >> 4, l7 = lane & 7;
  const int mbase = blockIdx.x * 128, nbase = blockIdx.y * 128;
  f32x4 acc[4][4] = {};
  for (int kt = 0; kt < 4; kt++) {
#pragma unroll
    for (int is = 0; is < 4; is++) {
      int row = is * 32 + (tid >> 3);
      int cl = tid & 7;
      int gc = cl ^ (row & 7);
      gload16(T + (size_t)(mbase + row) * CIN + kt * 64 + gc * 8,
              (char*)As + row * 128 + cl * 16);
      gload16(Wt + (size_t)(nbase + row) * CIN + kt * 64 + gc * 8,
              (char*)Bs + row * 128 + cl * 16);
    }
    __syncthreads();
#pragma unroll
    for (int ks = 0; ks < 2; ks++) {
      bf16x8 a[4], b[4];
#pragma unroll
      for (int m = 0; m < 4; m++)
        a[m] = *(const bf16x8*)((char*)As + (wr * 64 + m * 16 + l15) * 128 +
                                (((ks * 4 + h) ^ l7) * 16));
#pragma unroll
      for (int n = 0; n < 4; n++)
        b[n] = *(const bf16x8*)((char*)Bs + (wc * 64 + n * 16 + l15) * 128 +
                                (((ks * 4 + h) ^ l7) * 16));
#pragma unroll
      for (int m = 0; m < 4; m++)
#pragma unroll
        for (int n = 0; n < 4; n++) acc[m][n] = MFMA16(a[m], b[n], acc[m][n]);
    }
    __syncthreads();
  }
  // epilogue: bias + bf16 convert, coalesce through per-wave LDS region
  float bias_n[4];
#pragma unroll
  for (int n = 0; n < 4; n++) bias_n[n] = bias[nbase + wc * 64 + n * 16 + l15];
  unsigned short* ldso = (unsigned short*)(smem + w * 9216);  // [64][72] bf16
  const int b_idx = mbase / NTOK;
  const int ntok0 = mbase - b_idx * NTOK + wr * 64;
  const int a_idx = (nbase + wc * 64) >> 9;
  const int e0 = (nbase + wc * 64) & 511;
  const int p = b_idx * PAW + a_idx;
  if (vlayout == 0) {
#pragma unroll
    for (int m = 0; m < 4; m++)
#pragma unroll
      for (int n = 0; n < 4; n++)
#pragma unroll
        for (int r = 0; r < 4; r++)
          ldso[(m * 16 + h * 4 + r) * 72 + n * 16 + l15] =
              f2bf(acc[m][n][r] + bias_n[n]);
    __syncthreads();
#pragma unroll
    for (int pp = 0; pp < 8; pp++) {
      int q = pp * 8 + (lane >> 3);
      int ec = (lane & 7) * 8;
      *(bf16x8*)(Out + ((size_t)p * NTOK + ntok0 + q) * HID + e0 + ec) =
          *(const bf16x8*)(ldso + q * 72 + ec);
    }
  } else {
#pragma unroll
    for (int m = 0; m < 4; m++)
#pragma unroll
      for (int n = 0; n < 4; n++)
#pragma unroll
        for (int r = 0; r < 4; r++)
          ldso[(n * 16 + l15) * 72 + m * 16 + h * 4 + r] =
              f2bf(acc[m][n][r] + bias_n[n]);
    __syncthreads();
#pragma unroll
    for (int pp = 0; pp < 8; pp++) {
      int e = pp * 8 + (lane >> 3);
      int tc = (lane & 7) * 8;
      *(bf16x8*)(Out + ((size_t)p * HID + e0 + e) * NTOK + ntok0 + tc) =
          *(const bf16x8*)(ldso + e * 72 + tc);
    }
  }
}

// ---------------------------------------------------------------------------
// Flash attention.  1 block = 8 waves handles (local pair p, 64-row q-tile).
// Qb/Kb: (p, n, e) bf16.  Vt: (p, e, n) bf16.  Ob: rows (p/PAW)*2304+token,
// cols (p%PAW)*512+e, row stride PAW*512.  grid = CP*36 blocks.
// ---------------------------------------------------------------------------
#define PS_OFF 65536
#define RMAX_OFF 98304
#define RSUM_OFF 100352
#define MST_OFF 102400
#define LST_OFF 102656
#define SCL_OFF 102912

__global__ __launch_bounds__(512, 2) void flash_attn(
    const unsigned short* __restrict__ Qb, const unsigned short* __restrict__ Kb,
    const unsigned short* __restrict__ Vt, unsigned short* __restrict__ Ob,
    int PAW, int swz) {
  __shared__ __align__(16) char smem[103168];
  unsigned short* Ps = (unsigned short*)(smem + PS_OFF);  // [64][256] swizzled
  float* redmax = (float*)(smem + RMAX_OFF);              // [8][64]
  float* redsum = (float*)(smem + RSUM_OFF);              // [8][64]
  float* m_st = (float*)(smem + MST_OFF);                 // [64]
  float* l_st = (float*)(smem + LST_OFF);                 // [64]
  float* scl = (float*)(smem + SCL_OFF);                  // [64]

  const int i = blockIdx.x;
  int p, q0;
  if (swz) {  // pair%8 -> XCD for K/V L2 locality (CP multiple of 8)
    p = (i & 7) + 8 * ((i >> 3) / 36);
    q0 = ((i >> 3) % 36) * 64;
  } else {
    p = i / 36;
    q0 = (i % 36) * 64;
  }

  const int tid = threadIdx.x;
  const int w = tid >> 6, lane = tid & 63;
  const int l15 = lane & 15, h = lane >> 4, l7 = lane & 7;

  // stage Q tile (64 x 512) into LDS, XOR-swizzled via pre-swizzled source
#pragma unroll
  for (int rd = 0; rd < 8; rd++) {
    int row = rd * 8 + w;
    int gc = lane ^ (row & 7);
    gload16(Qb + ((size_t)p * NTOK + q0 + row) * HID + gc * 8,
            (char*)smem + row * 1024 + lane * 16);
  }
  if (tid < 64) {
    m_st[tid] = -INFINITY;
    l_st[tid] = 0.f;
  }
  f32x4 acc[4][4] = {};  // [q 4x16][e 4x16], this wave's e-slice = w*64
  __syncthreads();       // drains gload_lds (vmcnt 0) + init visible

  for (int kt = 0; kt < 9; kt++) {
    // ---- scores: this wave's 32-key slice over full hid=512
    const unsigned short* Kp =
        Kb + ((size_t)p * NTOK + kt * 256 + w * 32 + l15) * HID + h * 8;
    f32x4 S[4][2] = {};
#pragma unroll 4
    for (int ks = 0; ks < 16; ks++) {
      bf16x8 a[4];
#pragma unroll
      for (int m = 0; m < 4; m++)
        a[m] = *(const bf16x8*)((char*)smem + (m * 16 + l15) * 1024 +
                                (((ks * 4 + h) ^ l7) * 16));
#pragma unroll
      for (int kf = 0; kf < 2; kf++) {
        bf16x8 bk_ = *(const bf16x8*)(Kp + kf * 16 * HID + ks * 32);
#pragma unroll
        for (int m = 0; m < 4; m++) S[m][kf] = MFMA16(a[m], bk_, S[m][kf]);
      }
    }
    // partial row-max
#pragma unroll
    for (int m = 0; m < 4; m++)
#pragma unroll
      for (int r = 0; r < 4; r++) {
        float v = rmax16(fmaxf(S[m][0][r], S[m][1][r]));
        if (l15 == 0) redmax[w * 64 + m * 16 + h * 4 + r] = v;
      }
    __syncthreads();  // B1
    if (tid < 64) {
      float mo = m_st[tid];
      float mn = mo;
#pragma unroll
      for (int ww = 0; ww < 8; ww++) mn = fmaxf(mn, redmax[ww * 64 + tid]);
      scl[tid] = __expf(mo - mn);
      m_st[tid] = mn;
    }
    __syncthreads();  // B2
    // ---- P = exp(S - m), rescale acc, partial row-sum, write P to LDS
#pragma unroll
    for (int m = 0; m < 4; m++)
#pragma unroll
      for (int r = 0; r < 4; r++) {
        int q = m * 16 + h * 4 + r;
        float mn = m_st[q];
        float sc = scl[q];
        float p0 = __expf(S[m][0][r] - mn);
        float p1 = __expf(S[m][1][r] - mn);
#pragma unroll
        for (int n = 0; n < 4; n++) acc[m][n][r] *= sc;
        int kl0 = w * 32 + l15;
        int kl1 = kl0 + 16;
        Ps[q * 256 + (((kl0 >> 3) ^ (q & 7)) * 8) + (kl0 & 7)] = f2bf(p0);
        Ps[q * 256 + (((kl1 >> 3) ^ (q & 7)) * 8) + (kl1 & 7)] = f2bf(p1);
        float rs = rsum16(p0 + p1);
        if (l15 == 0) redsum[w * 64 + q] = rs;
      }
    __syncthreads();  // B3
    if (tid < 64) {
      float s = 0.f;
#pragma unroll
      for (int ww = 0; ww < 8; ww++) s += redsum[ww * 64 + tid];
      l_st[tid] = l_st[tid] * scl[tid] + s;
    }
    // ---- PV: acc(64 x 64-e-slice) += P(64x256) @ V(256 x e-slice)
    const unsigned short* Vp =
        Vt + ((size_t)p * HID + w * 64 + l15) * NTOK + kt * 256 + h * 8;
#pragma unroll
    for (int ks = 0; ks < 8; ks++) {
      bf16x8 pa[4];
#pragma unroll
      for (int m = 0; m < 4; m++)
        pa[m] = *(const bf16x8*)((char*)smem + PS_OFF + (m * 16 + l15) * 512 +
                                 (((ks * 4 + h) ^ l7) * 16));
#pragma unroll
      for (int n = 0; n < 4; n++) {
        bf16x8 bv_ = *(const bf16x8*)(Vp + n * 16 * NTOK + ks * 32);
#pragma unroll
        for (int m = 0; m < 4; m++) acc[m][n] = MFMA16(pa[m], bv_, acc[m][n]);
      }
    }
    // next iteration's B1 separates this PV from the next P overwrite
  }
  __syncthreads();  // final: PV done everywhere, l_st final
  // epilogue: O = acc / l, coalesce through per-wave LDS region
  unsigned short* ldso = (unsigned short*)(smem + w * 9216);  // [64][72] bf16
  float rl[4][4];
#pragma unroll
  for (int m = 0; m < 4; m++)
#pragma unroll
    for (int r = 0; r < 4; r++) rl[m][r] = 1.0f / l_st[m * 16 + h * 4 + r];
#pragma unroll
  for (int m = 0; m < 4; m++)
#pragma unroll
    for (int n = 0; n < 4; n++)
#pragma unroll
      for (int r = 0; r < 4; r++)
        ldso[(m * 16 + h * 4 + r) * 72 + n * 16 + l15] =
            f2bf(acc[m][n][r] * rl[m][r]);
  __syncthreads();
  const int pb = p / PAW, pa_ = p % PAW;
  const size_t OW = (size_t)PAW * 512;  // Ob row stride
  size_t base = ((size_t)pb * NTOK + q0) * OW + pa_ * 512 + w * 64;
#pragma unroll
  for (int pp = 0; pp < 8; pp++) {
    int q = pp * 8 + (lane >> 3);
    int ec = (lane & 7) * 8;
    *(bf16x8*)(Ob + base + (size_t)q * OW + ec) =
        *(const bf16x8*)(ldso + q * 72 + ec);
  }
}

// ---------------------------------------------------------------------------
// Output GEMM: out[b0+b][cout][n] (+)= Ob(tokens x OW) @ WoT[:, k0:k0+OW] + bo.
// WoT: (cout, k=4096) bf16 K-contig.  grid (tokens/64, 2), block 256.
// ---------------------------------------------------------------------------
__global__ __launch_bounds__(256, 2) void out_gemm(
    const unsigned short* __restrict__ Ob, const unsigned short* __restrict__ WoT,
    const float* __restrict__ bo, float* __restrict__ out, int OW, int k0,
    int accflag, int b0) {
  __shared__ __align__(16) char smem[36864];
  unsigned short* As = (unsigned short*)smem;  // [64][64]
  unsigned short* Bs = As + 64 * 64;           // [128][64]
  const int tid = threadIdx.x;
  const int w = tid >> 6, lane = tid & 63;
  const int wr = w >> 1, wc = w & 1;
  const int l15 = lane & 15, h = lane >> 4, l7 = lane & 7;
  const int mbase = blockIdx.x * 64, nbase = blockIdx.y * 128;
  const int nkt = OW >> 6;
  f32x4 acc[2][4] = {};
  for (int kt = 0; kt < nkt; kt++) {
#pragma unroll
    for (int is = 0; is < 2; is++) {
      int row = is * 32 + (tid >> 3);
      int cl = tid & 7, gc = cl ^ (row & 7);
      gload16(Ob + (size_t)(mbase + row) * OW + kt * 64 + gc * 8,
              (char*)As + row * 128 + cl * 16);
    }
#pragma unroll
    for (int is = 0; is < 4; is++) {
      int row = is * 32 + (tid >> 3);
      int cl = tid & 7, gc = cl ^ (row & 7);
      gload16(WoT + (size_t)(nbase + row) * DTOT + k0 + kt * 64 + gc * 8,
              (char*)Bs + row * 128 + cl * 16);
    }
    __syncthreads();
#pragma unroll
    for (int ks = 0; ks < 2; ks++) {
      bf16x8 a[2], b[4];
#pragma unroll
      for (int m = 0; m < 2; m++)
        a[m] = *(const bf16x8*)((char*)As + (wr * 32 + m * 16 + l15) * 128 +
                                (((ks * 4 + h) ^ l7) * 16));
#pragma unroll
      for (int n = 0; n < 4; n++)
        b[n] = *(const bf16x8*)((char*)Bs + (wc * 64 + n * 16 + l15) * 128 +
                                (((ks * 4 + h) ^ l7) * 16));
#pragma unroll
      for (int m = 0; m < 2; m++)
#pragma unroll
        for (int n = 0; n < 4; n++) acc[m][n] = MFMA16(a[m], b[n], acc[m][n]);
    }
    __syncthreads();
  }
  float bias_n[4];
#pragma unroll
  for (int n = 0; n < 4; n++)
    bias_n[n] = accflag ? 0.f : bo[nbase + wc * 64 + n * 16 + l15];
  float* ldsoF = (float*)(smem + w * 9216);  // [64 cout][36 n] f32
#pragma unroll
  for (int m = 0; m < 2; m++)
#pragma unroll
    for (int n = 0; n < 4; n++)
#pragma unroll
      for (int r = 0; r < 4; r++)
        ldsoF[(n * 16 + l15) * 36 + m * 16 + h * 4 + r] =
            acc[m][n][r] + bias_n[n];
  __syncthreads();
  const int b_idx = mbase / NTOK;
  const int n0 = mbase - b_idx * NTOK + wr * 32;
  const int c0 = nbase + wc * 64;
#pragma unroll
  for (int pp = 0; pp < 8; pp++) {
    int cout = pp * 8 + (lane >> 3);
    int nc = (lane & 7) * 4;
    f32x4 v = *(const f32x4*)&ldsoF[cout * 36 + nc];
    float* dst = &out[((size_t)(b0 + b_idx) * CIN + c0 + cout) * NTOK + n0 + nc];
    if (accflag) {
      f32x4 old = *(const f32x4*)dst;
      *(f32x4*)dst = old + v;
    } else {
      *(f32x4*)dst = v;
    }
  }
}

// ---------------------------------------------------------------------------
extern "C" void kernel_launch(void* const* d_in, const int* in_sizes, int n_in,
                              void* d_out, int out_size, void* d_ws,
                              size_t ws_size, hipStream_t stream) {
  const float* x = (const float*)d_in[0];
  const float* Wq = (const float*)d_in[1];
  const float* bq = (const float*)d_in[2];
  const float* Wk = (const float*)d_in[3];
  const float* bk = (const float*)d_in[4];
  const float* Wv = (const float*)d_in[5];
  const float* bv = (const float*)d_in[6];
  const float* Wo = (const float*)d_in[7];
  const float* bo = (const float*)d_in[8];
  float* out = (float*)d_out;

  // ---- choose chunk size CP (pairs per chunk) from ws_size (deterministic)
  const size_t ws_el = ws_size / 2;  // bf16 elements
  const size_t W_EL = (size_t)4 * 1048576;  // WqT,WkT,WvT,WoT
  int CP = 0;
  const int cands[6] = {32, 16, 8, 4, 2, 1};
  for (int ci = 0; ci < 6; ci++) {
    int cp = cands[ci];
    int g = cp >= 8 ? cp / 8 : 1;
    int paw = cp < 8 ? cp : 8;
    size_t need = W_EL + (size_t)g * NTOK * CIN +
                  (size_t)3 * cp * NTOK * HID +
                  (size_t)g * NTOK * paw * HID;
    if (need <= ws_el) { CP = cp; break; }
  }
  if (CP == 0) return;  // ws too small even for 1-pair chunks (19 MB)
  const int G = CP >= 8 ? CP / 8 : 1;
  const int PAW = CP < 8 ? CP : 8;

  // ---- workspace layout (bf16 elements)
  unsigned short* WqT = (unsigned short*)d_ws;      // 4096 x 256
  unsigned short* WkT = WqT + 1048576;
  unsigned short* WvT = WkT + 1048576;
  unsigned short* WoT = WvT + 1048576;              // 256 x 4096 (cout, k)
  unsigned short* tbc = WoT + 1048576;              // G*2304 x 256
  unsigned short* Qc = tbc + (size_t)G * NTOK * CIN;  // CP x 2304 x 512
  unsigned short* Kc = Qc + (size_t)CP * NTOK * HID;
  unsigned short* Vc = Kc + (size_t)CP * NTOK * HID;
  unsigned short* Oc = Vc + (size_t)CP * NTOK * HID;  // G*2304 x PAW*512

  dim3 tp(32, 8);
  transpose_to_bf16<<<dim3(128, 8), tp, 0, stream>>>(Wq, WqT, CIN, DTOT);
  transpose_to_bf16<<<dim3(128, 8), tp, 0, stream>>>(Wk, WkT, CIN, DTOT);
  transpose_to_bf16<<<dim3(128, 8), tp, 0, stream>>>(Wv, WvT, CIN, DTOT);
  transpose_to_bf16<<<dim3(8, 128), tp, 0, stream>>>(Wo, WoT, DTOT, CIN);

  for (int pair0 = 0; pair0 < 32; pair0 += CP) {
    const int b0 = pair0 >> 3, a0 = pair0 & 7;
    for (int gi = 0; gi < G; gi++)
      transpose_to_bf16<<<dim3(72, 8), tp, 0, stream>>>(
          x + (size_t)(b0 + gi) * CIN * NTOK, tbc + (size_t)gi * NTOK * CIN,
          CIN, NTOK);
    dim3 pg(18 * G, PAW * 4);
    proj_gemm<<<pg, 256, 0, stream>>>(tbc, WqT + (size_t)a0 * 512 * CIN,
                                      bq + a0 * 512, Qc, 0, PAW);
    proj_gemm<<<pg, 256, 0, stream>>>(tbc, WkT + (size_t)a0 * 512 * CIN,
                                      bk + a0 * 512, Kc, 0, PAW);
    proj_gemm<<<pg, 256, 0, stream>>>(tbc, WvT + (size_t)a0 * 512 * CIN,
                                      bv + a0 * 512, Vc, 1, PAW);
    flash_attn<<<dim3(CP * 36), 512, 0, stream>>>(Qc, Kc, Vc, Oc, PAW,
                                                  (CP & 7) == 0 ? 1 : 0);
    out_gemm<<<dim3(36 * G, 2), 256, 0, stream>>>(Oc, WoT, bo, out, PAW * 512,
                                                  a0 * 512, a0 != 0 ? 1 : 0,
                                                  b0);
  }
}